// Round 16
// baseline (217.046 us; speedup 1.0000x reference)
//
#include <hip/hip_runtime.h>
#include <hip/hip_bf16.h>

// FALayer: z[v] = sum_{(u->v)} h[u] * e_uv,
//   e_uv = tanh(w_dst . h[v] + w_src . h[u] + b) * deg[v] * deg[u]
//
// Pipeline (4 dispatches):
//  1) prep: zero subcur/ovf_cnt; one wave/node -> ad[n]=(w_dst.h+b, deg),
//     bd[n]=(w_src.h, deg); optionally hb[n]=bf16(h[n]) (ws_size permitting).
//  2) binscatter: append (src|dstLocal) 4B to XCD-private sub-bin
//     (bin = dst>>7, part = blockIdx&7). Sequential same-XCD appends ->
//     HBM write ~= real bytes (~4 MB), vs 49 MB for random bucket writes
//     (R13/R15: 800k temporally-scattered 4B writes = 800k x 64B lines,
//     ~1 TB/s, 51 us, invariant under 4x ILP -> traffic-bound, not latency).
//  3) permute: block per bin; read 8 sub-bins seq; e = tanh(ad+bd)*deg*deg
//     (ad in LDS, bd L2-hot); slot via LDS counters (no global atomics);
//     write bucket (bin's region = 16KB contiguous, one CU -> dense);
//     write per-node counts to cursor.
//  4) aggregate (bf16 or fp32): wave per node, multi-slot unrolled gathers,
//     shfl combine; unconditional tail scan of tiny ovf list; no z atomics.
//
// WS budget lesson (R5/R7): NEVER exceed ws_size (28.6 MB unchecked usage
// corrupted adjacent allocations). Core layout ~11.7 MB; hb (12.8 MB) last,
// enabled ONLY if the exact end offset fits ws_size.
//
// Packing: src fits 16 bits (N=50000<65536); dstLocal 7 bits (128-node bins);
// |e|<1 strictly (tanh<1, deg<1) -> q15, error 3e-5 << 0.24 threshold.

#define DFEAT 128
#define CAP 32
#define SUBCAP 320      // per sub-bin; lambda=256, +4sigma
#define NPART 8
#define BINSHIFT 7      // 128 nodes per bin
#define OVF_CAP 16384

__device__ __forceinline__ int load_idx_nt(const void* p, int k, int is64) {
    if (is64) return (int)__builtin_nontemporal_load((const long long*)p + k);
    return __builtin_nontemporal_load((const int*)p + k);
}

// Wave-local dtype sniff on odd 32-bit words (values < 2^31, LE => int64 iff all 0).
__device__ __forceinline__ int detect_is64(const int* v) {
    int lane = threadIdx.x & 63;
    int x = v[2 * lane + 1];
    return (__ballot(x != 0) == 0ull) ? 1 : 0;
}

__device__ __forceinline__ unsigned short f2bf(float f) {
    unsigned u = __float_as_uint(f);
    u += 0x7FFF + ((u >> 16) & 1);   // RNE
    return (unsigned short)(u >> 16);
}
__device__ __forceinline__ float blo(unsigned u) { return __uint_as_float(u << 16); }
__device__ __forceinline__ float bhi(unsigned u) { return __uint_as_float(u & 0xFFFF0000u); }

// One wave per node: partial gates (+ optional bf16 h copy) + zero counters.
__global__ void prep_kernel(const float* __restrict__ h,
                            const float* __restrict__ deg,
                            const float* __restrict__ gw,
                            const float* __restrict__ gb,
                            float2* __restrict__ ad, float2* __restrict__ bd,
                            unsigned short* __restrict__ hb,   // may be null
                            int* __restrict__ subcur, int* __restrict__ ovf_cnt,
                            int N, int nsub) {
    int tid = blockIdx.x * blockDim.x + threadIdx.x;
    int stride = gridDim.x * blockDim.x;
    for (int i = tid; i < nsub; i += stride) subcur[i] = 0;
    if (tid == 0) *ovf_cnt = 0;

    int lane = threadIdx.x & 63;
    int wavesTotal = stride >> 6;
    int wave0 = tid >> 6;
    float2 wA = *(const float2*)(gw + 2 * lane);
    float2 wB = *(const float2*)(gw + DFEAT + 2 * lane);
    float bias = gb[0];
    for (int n = wave0; n < N; n += wavesTotal) {
        float2 v = *(const float2*)(h + (size_t)n * DFEAT + 2 * lane);
        float pa = v.x * wA.x + v.y * wA.y;
        float pb = v.x * wB.x + v.y * wB.y;
        if (hb) {
            unsigned pack = (unsigned)f2bf(v.x) | ((unsigned)f2bf(v.y) << 16);
            ((unsigned*)(hb + (size_t)n * DFEAT))[lane] = pack;
        }
        for (int off = 32; off; off >>= 1) {
            pa += __shfl_xor(pa, off, 64);
            pb += __shfl_xor(pb, off, 64);
        }
        if (lane == 0) {
            float dg = deg[n];
            ad[n] = make_float2(pa + bias, dg);
            bd[n] = make_float2(pb, dg);
        }
    }
}

// Pass 1: append (src | dstLocal<<16) to XCD-private sub-bin. Sequential
// same-partition appends -> lines combine in that XCD's L2, evict once.
__global__ void binscatter_kernel(const void* __restrict__ src, const void* __restrict__ dst,
                                  const float2* __restrict__ ad, const float2* __restrict__ bd,
                                  int* __restrict__ subcur, int* __restrict__ ovf_cnt,
                                  int4* __restrict__ ovf, unsigned* __restrict__ binbuf, int E) {
    int is64 = detect_is64((const int*)src);
    int part = blockIdx.x & (NPART - 1);
    int stride = gridDim.x * blockDim.x;
    for (int k = blockIdx.x * blockDim.x + threadIdx.x; k < E; k += stride) {
        int s = load_idx_nt(src, k, is64);
        int d = load_idx_nt(dst, k, is64);
        int sub = ((d >> BINSHIFT) << 3) | part;
        int pos = atomicAdd(&subcur[sub], 1);
        if (pos < SUBCAP) {
            binbuf[(size_t)sub * SUBCAP + pos] =
                (unsigned)s | ((unsigned)(d & ((1 << BINSHIFT) - 1)) << 16);
        } else {                      // ~never (lambda=256, cap=320)
            float2 A = ad[d]; float2 B = bd[s];
            float e = tanhf(A.x + B.x) * A.y * B.y;
            int t = atomicAdd(ovf_cnt, 1);
            if (t < OVF_CAP) ovf[t] = make_int4(d, s, __float_as_int(e), 0);
        }
    }
}

// Pass 2: block per bin. Read 8 sub-bins sequentially, compute e, assign
// slots with LDS counters, write node-major bucket (dense 16KB region/bin),
// then write per-node counts to cursor.
__global__ void __launch_bounds__(256) permute_kernel(
        const unsigned* __restrict__ binbuf, const int* __restrict__ subcur,
        const float2* __restrict__ ad, const float2* __restrict__ bd,
        int* __restrict__ cursor, int* __restrict__ ovf_cnt, int4* __restrict__ ovf,
        unsigned* __restrict__ bucket, int N) {
    int bin = blockIdx.x;
    int binBase = bin << BINSHIFT;
    __shared__ float2 adl[1 << BINSHIFT];
    __shared__ int cnt[1 << BINSHIFT];
    int t = threadIdx.x;
    if (t < (1 << BINSHIFT)) {
        int d = binBase + t;
        adl[t] = (d < N) ? ad[d] : make_float2(0.f, 0.f);
        cnt[t] = 0;
    }
    __syncthreads();

    for (int p = 0; p < NPART; p++) {
        int sub = bin * NPART + p;
        int c = subcur[sub]; if (c > SUBCAP) c = SUBCAP;
        const unsigned* bb = binbuf + (size_t)sub * SUBCAP;
        for (int i = t; i < c; i += 256) {
            unsigned en = bb[i];
            int s = en & 0xFFFF;
            int dl = (en >> 16) & ((1 << BINSHIFT) - 1);
            float2 A = adl[dl];
            float2 B = bd[s];
            float e = tanhf(A.x + B.x) * A.y * B.y;
            int slot = atomicAdd(&cnt[dl], 1);
            int d = binBase + dl;
            if (slot < CAP) {
                int eq = __float2int_rn(e * 32767.0f);
                bucket[(size_t)d * CAP + slot] =
                    (unsigned)s | ((unsigned)(eq & 0xFFFF) << 16);
            } else {                  // node degree > CAP (rare)
                int tt = atomicAdd(ovf_cnt, 1);
                if (tt < OVF_CAP) ovf[tt] = make_int4(d, s, __float_as_int(e), 0);
            }
        }
    }
    __syncthreads();
    if (t < (1 << BINSHIFT)) {
        int d = binBase + t;
        if (d < N) cursor[d] = cnt[t];
    }
}

// fp32-h variant. Wave per node (4/block). lane&31 = float4 chunk, lane>>5 = slot.
__global__ void __launch_bounds__(256) aggregate_f32(
        const float* __restrict__ h,
        const unsigned* __restrict__ bucket,
        const int* __restrict__ cursor,
        const int4* __restrict__ ovf, const int* __restrict__ ovf_cnt,
        float* __restrict__ z, int N) {
    int wid = threadIdx.x >> 6;
    int v = blockIdx.x * 4 + wid;
    if (v >= N) return;
    int lane = threadIdx.x & 63;
    int sub = lane & 31;
    int slot = lane >> 5;
    int cntfull = cursor[v];
    int cnt = cntfull > CAP ? CAP : cntfull;
    const unsigned* bk = bucket + (size_t)v * CAP;
    const float inv = 1.0f / 32767.0f;

    float4 acc = make_float4(0.f, 0.f, 0.f, 0.f);
    int o = slot;
    for (; o + 6 < cnt; o += 8) {
        unsigned p0 = bk[o], p1 = bk[o + 2], p2 = bk[o + 4], p3 = bk[o + 6];
        float4 g0 = *(const float4*)(h + (size_t)(p0 & 0xFFFF) * DFEAT + sub * 4);
        float4 g1 = *(const float4*)(h + (size_t)(p1 & 0xFFFF) * DFEAT + sub * 4);
        float4 g2 = *(const float4*)(h + (size_t)(p2 & 0xFFFF) * DFEAT + sub * 4);
        float4 g3 = *(const float4*)(h + (size_t)(p3 & 0xFFFF) * DFEAT + sub * 4);
        float e0 = (float)((int)p0 >> 16) * inv;
        float e1 = (float)((int)p1 >> 16) * inv;
        float e2 = (float)((int)p2 >> 16) * inv;
        float e3 = (float)((int)p3 >> 16) * inv;
        acc.x += g0.x * e0 + g1.x * e1 + g2.x * e2 + g3.x * e3;
        acc.y += g0.y * e0 + g1.y * e1 + g2.y * e2 + g3.y * e3;
        acc.z += g0.z * e0 + g1.z * e1 + g2.z * e2 + g3.z * e3;
        acc.w += g0.w * e0 + g1.w * e1 + g2.w * e2 + g3.w * e3;
    }
    for (; o < cnt; o += 2) {
        unsigned p = bk[o];
        float4 g = *(const float4*)(h + (size_t)(p & 0xFFFF) * DFEAT + sub * 4);
        float e = (float)((int)p >> 16) * inv;
        acc.x += g.x * e; acc.y += g.y * e; acc.z += g.z * e; acc.w += g.w * e;
    }

    acc.x += __shfl_xor(acc.x, 32, 64);
    acc.y += __shfl_xor(acc.y, 32, 64);
    acc.z += __shfl_xor(acc.z, 32, 64);
    acc.w += __shfl_xor(acc.w, 32, 64);

    if (slot == 0) {
        int n = *ovf_cnt; if (n > OVF_CAP) n = OVF_CAP;   // ~always 0..tens
        for (int t = 0; t < n; t++) {
            int4 p = ovf[t];
            if (p.x == v) {
                float e = __int_as_float(p.z);
                float4 g = *(const float4*)(h + (size_t)p.y * DFEAT + sub * 4);
                acc.x += g.x * e; acc.y += g.y * e;
                acc.z += g.z * e; acc.w += g.w * e;
            }
        }
        *(float4*)(z + (size_t)v * DFEAT + sub * 4) = acc;
    }
}

// bf16-h variant. lane&15 = 8-feature chunk, lane>>4 = slot (4 slots, unroll 2).
__global__ void __launch_bounds__(256) aggregate_bf16(
        const unsigned short* __restrict__ hb,
        const unsigned* __restrict__ bucket,
        const int* __restrict__ cursor,
        const int4* __restrict__ ovf, const int* __restrict__ ovf_cnt,
        float* __restrict__ z, int N) {
    int wid = threadIdx.x >> 6;
    int v = blockIdx.x * 4 + wid;
    if (v >= N) return;
    int lane = threadIdx.x & 63;
    int sub = lane & 15;
    int slot = lane >> 4;
    int cntfull = cursor[v];
    int cnt = cntfull > CAP ? CAP : cntfull;
    const unsigned* bk = bucket + (size_t)v * CAP;
    const float inv = 1.0f / 32767.0f;

    float a0=0,a1=0,a2=0,a3=0,a4=0,a5=0,a6=0,a7=0;
    int o = slot;
    for (; o + 4 < cnt; o += 8) {
        unsigned p0 = bk[o], p1 = bk[o + 4];
        uint4 g0 = *(const uint4*)(hb + (size_t)(p0 & 0xFFFF) * DFEAT + sub * 8);
        uint4 g1 = *(const uint4*)(hb + (size_t)(p1 & 0xFFFF) * DFEAT + sub * 8);
        float e0 = (float)((int)p0 >> 16) * inv;
        float e1 = (float)((int)p1 >> 16) * inv;
        a0 += blo(g0.x) * e0 + blo(g1.x) * e1;
        a1 += bhi(g0.x) * e0 + bhi(g1.x) * e1;
        a2 += blo(g0.y) * e0 + blo(g1.y) * e1;
        a3 += bhi(g0.y) * e0 + bhi(g1.y) * e1;
        a4 += blo(g0.z) * e0 + blo(g1.z) * e1;
        a5 += bhi(g0.z) * e0 + bhi(g1.z) * e1;
        a6 += blo(g0.w) * e0 + blo(g1.w) * e1;
        a7 += bhi(g0.w) * e0 + bhi(g1.w) * e1;
    }
    for (; o < cnt; o += 4) {
        unsigned p = bk[o];
        uint4 g = *(const uint4*)(hb + (size_t)(p & 0xFFFF) * DFEAT + sub * 8);
        float e = (float)((int)p >> 16) * inv;
        a0 += blo(g.x) * e; a1 += bhi(g.x) * e;
        a2 += blo(g.y) * e; a3 += bhi(g.y) * e;
        a4 += blo(g.z) * e; a5 += bhi(g.z) * e;
        a6 += blo(g.w) * e; a7 += bhi(g.w) * e;
    }

    a0 += __shfl_xor(a0, 16, 64); a1 += __shfl_xor(a1, 16, 64);
    a2 += __shfl_xor(a2, 16, 64); a3 += __shfl_xor(a3, 16, 64);
    a4 += __shfl_xor(a4, 16, 64); a5 += __shfl_xor(a5, 16, 64);
    a6 += __shfl_xor(a6, 16, 64); a7 += __shfl_xor(a7, 16, 64);
    a0 += __shfl_xor(a0, 32, 64); a1 += __shfl_xor(a1, 32, 64);
    a2 += __shfl_xor(a2, 32, 64); a3 += __shfl_xor(a3, 32, 64);
    a4 += __shfl_xor(a4, 32, 64); a5 += __shfl_xor(a5, 32, 64);
    a6 += __shfl_xor(a6, 32, 64); a7 += __shfl_xor(a7, 32, 64);

    if (slot == 0) {
        int n = *ovf_cnt; if (n > OVF_CAP) n = OVF_CAP;   // ~always 0..tens
        for (int t = 0; t < n; t++) {
            int4 p = ovf[t];
            if (p.x == v) {
                float e = __int_as_float(p.z);
                uint4 g = *(const uint4*)(hb + (size_t)p.y * DFEAT + sub * 8);
                a0 += blo(g.x) * e; a1 += bhi(g.x) * e;
                a2 += blo(g.y) * e; a3 += bhi(g.y) * e;
                a4 += blo(g.z) * e; a5 += bhi(g.z) * e;
                a6 += blo(g.w) * e; a7 += bhi(g.w) * e;
            }
        }
        float* zp = z + (size_t)v * DFEAT + sub * 8;
        *(float4*)zp       = make_float4(a0, a1, a2, a3);
        *(float4*)(zp + 4) = make_float4(a4, a5, a6, a7);
    }
}

extern "C" void kernel_launch(void* const* d_in, const int* in_sizes, int n_in,
                              void* d_out, int out_size, void* d_ws, size_t ws_size,
                              hipStream_t stream) {
    const float* h      = (const float*)d_in[0];
    const float* deg    = (const float*)d_in[1];
    const float* gate_w = (const float*)d_in[2];
    const float* gate_b = (const float*)d_in[3];
    const void*  src    = d_in[4];
    const void*  dst    = d_in[5];
    float* z = (float*)d_out;

    const int N = in_sizes[1];   // 50000 (< 65536 required for 16-bit src pack)
    const int E = in_sizes[4];   // 800000
    const int nbins = (N + (1 << BINSHIFT) - 1) >> BINSHIFT;  // 391
    const int nsub  = nbins * NPART;                          // 3128

    auto align_up = [](size_t x) { return (x + 255) & ~(size_t)255; };
    size_t off = 0;
    auto carve = [&](size_t bytes) { size_t o = off; off += align_up(bytes); return o; };
    char* base = (char*)d_ws;
    float2*   ad      = (float2*)(base + carve((size_t)N * 8));
    float2*   bd      = (float2*)(base + carve((size_t)N * 8));
    int*      cursor  = (int*)(base + carve((size_t)N * 4));
    int*      ovf_cnt = (int*)(base + carve(256));
    int*      subcur  = (int*)(base + carve((size_t)nsub * 4));
    unsigned* bucket  = (unsigned*)(base + carve((size_t)N * CAP * 4));
    unsigned* binbuf  = (unsigned*)(base + carve((size_t)nsub * SUBCAP * 4));
    int4*     ovf     = (int4*)(base + carve((size_t)OVF_CAP * 16));
    // core ~11.7 MB. hb goes last, only if it FITS:
    size_t hb_off = carve((size_t)N * DFEAT * 2);
    bool use_bf16 = (off <= ws_size);        // exact check against ws_size
    unsigned short* hb = use_bf16 ? (unsigned short*)(base + hb_off) : nullptr;

    prep_kernel<<<2048, 256, 0, stream>>>(h, deg, gate_w, gate_b, ad, bd, hb,
                                          subcur, ovf_cnt, N, nsub);

    binscatter_kernel<<<2048, 256, 0, stream>>>(src, dst, ad, bd, subcur, ovf_cnt,
                                                ovf, binbuf, E);

    permute_kernel<<<nbins, 256, 0, stream>>>(binbuf, subcur, ad, bd, cursor,
                                              ovf_cnt, ovf, bucket, N);

    if (use_bf16) {
        aggregate_bf16<<<(N + 3) / 4, 256, 0, stream>>>(hb, bucket, cursor,
                                                        ovf, ovf_cnt, z, N);
    } else {
        aggregate_f32<<<(N + 3) / 4, 256, 0, stream>>>(h, bucket, cursor,
                                                       ovf, ovf_cnt, z, N);
    }
}

// Round 18
// 172.298 us; speedup vs baseline: 1.2597x; 1.2597x over previous
//
#include <hip/hip_runtime.h>
#include <hip/hip_bf16.h>

// FALayer: z[v] = sum_{(u->v)} h[u] * e_uv,
//   e_uv = tanh(w_dst . h[v] + w_src . h[u] + b) * deg[v] * deg[u]
//
// Pipeline (4 dispatches):
//  0) memset 512B: subcur[64] + ovf_cnt
//  1) fused: [blocks 0..SCB) binscatter | [SCB..) prep gates + bf16 h copy.
//     binscatter: 2048 contiguous edges/block; LDS histogram over 49
//     1024-node bins; ONE global atomicAdd per bin per block (19k total --
//     R16's 800k atomics over 3128 hot counters serialized at ~0.42 TB/s,
//     VALU 0.6%); group write is dense (~42 entries, full lines, one CU).
//  2) permute: block(1024) per bin; read bin region sequentially; e =
//     tanh(ad+bd)*deg*deg (ad in LDS, bd L2-hot); slot via LDS counters (no
//     global atomics); write bin's contiguous 128KB bucket region + cursor.
//  3) aggregate (bf16/fp32): wave per node, unrolled gathers, shfl combine;
//     tail-scan tiny ovf list (flag=1 entries compute e from ad/bd).
//
// R13/R15/R16 scatter history: 1-edge/thread 56us; 4x ILP null (51us, occ
// 22% -> not latency); XCD sub-bins 78us (atomic hotspot). Root causes:
// per-edge global atomics + temporally-scattered partial-line writes. This
// version: 42x fewer global atomics, dense group writes.
//
// WS lesson (R5/R7): NEVER exceed ws_size. Core ~12.7 MB; hb (12.8 MB) last,
// enabled ONLY if exact end offset fits ws_size.
// Packing: src 16 bits (N<65536); dstLocal 10 bits; |e|<1 -> q15.

#define DFEAT 128
#define CAP 32
#define BIN_SHIFT 10            // 1024 nodes per bin
#define NBINS_MAX 64            // N<=65536
#define BINCAP 18432            // lambda=16327, +~16 sigma
#define EPT 8                   // edges per thread in binscatter
#define OVF_CAP 16384

__device__ __forceinline__ int detect_is64(const int* v) {
    int lane = threadIdx.x & 63;
    int x = v[2 * lane + 1];
    return (__ballot(x != 0) == 0ull) ? 1 : 0;
}

__device__ __forceinline__ unsigned short f2bf(float f) {
    unsigned u = __float_as_uint(f);
    u += 0x7FFF + ((u >> 16) & 1);   // RNE
    return (unsigned short)(u >> 16);
}
__device__ __forceinline__ float blo(unsigned u) { return __uint_as_float(u << 16); }
__device__ __forceinline__ float bhi(unsigned u) { return __uint_as_float(u & 0xFFFF0000u); }

// ---- fused kernel: binscatter blocks [0, scb) ; prep blocks [scb, grid) ----
__global__ void fused_kernel(const float* __restrict__ h,
                             const float* __restrict__ deg,
                             const float* __restrict__ gw,
                             const float* __restrict__ gb,
                             const void* __restrict__ src, const void* __restrict__ dst,
                             float2* __restrict__ ad, float2* __restrict__ bd,
                             unsigned short* __restrict__ hb,   // may be null
                             int* __restrict__ subcur, int* __restrict__ ovf_cnt,
                             int4* __restrict__ ovf, unsigned* __restrict__ binbuf,
                             int N, int E, int scb, int prepBlocks) {
    if ((int)blockIdx.x < scb) {
        // ---------------- binscatter ----------------
        __shared__ int lcnt[NBINS_MAX];
        __shared__ int lrun[NBINS_MAX];
        __shared__ int gbase[NBINS_MAX];
        int t = threadIdx.x;
        int is64 = detect_is64((const int*)src);
        if (t < NBINS_MAX) { lcnt[t] = 0; lrun[t] = 0; }
        __syncthreads();

        int k0 = (blockIdx.x * 256 + t) * EPT;
        int s[EPT], d[EPT], bin[EPT];
        bool full = (k0 + EPT <= E);
        if (full) {
            if (is64) {
                #pragma unroll
                for (int i = 0; i < EPT; i += 2) {
                    longlong2 sv = *(const longlong2*)((const long long*)src + k0 + i);
                    longlong2 dv = *(const longlong2*)((const long long*)dst + k0 + i);
                    s[i] = (int)sv.x; s[i + 1] = (int)sv.y;
                    d[i] = (int)dv.x; d[i + 1] = (int)dv.y;
                }
            } else {
                #pragma unroll
                for (int i = 0; i < EPT; i += 4) {
                    int4 sv = *(const int4*)((const int*)src + k0 + i);
                    int4 dv = *(const int4*)((const int*)dst + k0 + i);
                    s[i] = sv.x; s[i+1] = sv.y; s[i+2] = sv.z; s[i+3] = sv.w;
                    d[i] = dv.x; d[i+1] = dv.y; d[i+2] = dv.z; d[i+3] = dv.w;
                }
            }
            #pragma unroll
            for (int i = 0; i < EPT; i++) bin[i] = d[i] >> BIN_SHIFT;
        } else {
            #pragma unroll
            for (int i = 0; i < EPT; i++) {
                int k = k0 + i;
                if (k < E) {
                    s[i] = is64 ? (int)((const long long*)src)[k] : ((const int*)src)[k];
                    d[i] = is64 ? (int)((const long long*)dst)[k] : ((const int*)dst)[k];
                    bin[i] = d[i] >> BIN_SHIFT;
                } else bin[i] = -1;
            }
        }
        #pragma unroll
        for (int i = 0; i < EPT; i++)
            if (bin[i] >= 0) atomicAdd(&lcnt[bin[i]], 1);
        __syncthreads();
        if (t < NBINS_MAX) {
            int c = lcnt[t];
            gbase[t] = (c > 0) ? atomicAdd(&subcur[t], c) : 0;
        }
        __syncthreads();
        #pragma unroll
        for (int i = 0; i < EPT; i++) {
            if (bin[i] < 0) continue;
            int pos = atomicAdd(&lrun[bin[i]], 1);
            int g = gbase[bin[i]] + pos;
            if (g < BINCAP) {
                binbuf[(size_t)bin[i] * BINCAP + g] =
                    (unsigned)s[i] | ((unsigned)(d[i] & ((1 << BIN_SHIFT) - 1)) << 16);
            } else {                      // ~never
                int tt = atomicAdd(ovf_cnt, 1);
                if (tt < OVF_CAP) ovf[tt] = make_int4(d[i], s[i], 0, 1);
            }
        }
    } else {
        // ---------------- prep: gates + optional bf16 copy ----------------
        int pb = blockIdx.x - scb;
        int tid = pb * 256 + threadIdx.x;
        int lane = threadIdx.x & 63;
        int wavesTotal = (prepBlocks * 256) >> 6;
        int wave0 = tid >> 6;
        float2 wA = *(const float2*)(gw + 2 * lane);
        float2 wB = *(const float2*)(gw + DFEAT + 2 * lane);
        float bias = gb[0];
        for (int n = wave0; n < N; n += wavesTotal) {
            float2 v = *(const float2*)(h + (size_t)n * DFEAT + 2 * lane);
            float pa = v.x * wA.x + v.y * wA.y;
            float pb2 = v.x * wB.x + v.y * wB.y;
            if (hb) {
                unsigned pack = (unsigned)f2bf(v.x) | ((unsigned)f2bf(v.y) << 16);
                ((unsigned*)(hb + (size_t)n * DFEAT))[lane] = pack;
            }
            for (int off = 32; off; off >>= 1) {
                pa += __shfl_xor(pa, off, 64);
                pb2 += __shfl_xor(pb2, off, 64);
            }
            if (lane == 0) {
                float dg = deg[n];
                ad[n] = make_float2(pa + bias, dg);
                bd[n] = make_float2(pb2, dg);
            }
        }
    }
}

// ---- permute: block(1024) per bin -> bucket + cursor, no global atomics ----
__global__ void __launch_bounds__(1024) permute_kernel(
        const unsigned* __restrict__ binbuf, const int* __restrict__ subcur,
        const float2* __restrict__ ad, const float2* __restrict__ bd,
        int* __restrict__ cursor, int* __restrict__ ovf_cnt, int4* __restrict__ ovf,
        unsigned* __restrict__ bucket, int N) {
    int bin = blockIdx.x;
    int binBase = bin << BIN_SHIFT;
    __shared__ float2 adl[1 << BIN_SHIFT];
    __shared__ int cnt[1 << BIN_SHIFT];
    int t = threadIdx.x;
    {
        int d = binBase + t;
        adl[t] = (d < N) ? ad[d] : make_float2(0.f, 0.f);
        cnt[t] = 0;
    }
    __syncthreads();

    int c = subcur[bin]; if (c > BINCAP) c = BINCAP;
    const unsigned* bb = binbuf + (size_t)bin * BINCAP;
    for (int i = t; i < c; i += 1024) {
        unsigned en = bb[i];
        int s = en & 0xFFFF;
        int dl = en >> 16;
        float2 A = adl[dl];
        float2 B = bd[s];
        float e = tanhf(A.x + B.x) * A.y * B.y;
        int slot = atomicAdd(&cnt[dl], 1);
        int d = binBase + dl;
        if (slot < CAP) {
            int eq = __float2int_rn(e * 32767.0f);
            bucket[(size_t)d * CAP + slot] = (unsigned)s | ((unsigned)(eq & 0xFFFF) << 16);
        } else {
            int tt = atomicAdd(ovf_cnt, 1);
            if (tt < OVF_CAP) ovf[tt] = make_int4(d, s, __float_as_int(e), 0);
        }
    }
    __syncthreads();
    {
        int d = binBase + t;
        if (d < N) cursor[d] = cnt[t];
    }
}

// ---- aggregate (bf16 h). lane&15 = 8-feat chunk, lane>>4 = slot. ----
__global__ void __launch_bounds__(256) aggregate_bf16(
        const unsigned short* __restrict__ hb,
        const unsigned* __restrict__ bucket,
        const int* __restrict__ cursor,
        const float2* __restrict__ ad, const float2* __restrict__ bd,
        const int4* __restrict__ ovf, const int* __restrict__ ovf_cnt,
        float* __restrict__ z, int N) {
    int wid = threadIdx.x >> 6;
    int v = blockIdx.x * 4 + wid;
    if (v >= N) return;
    int lane = threadIdx.x & 63;
    int sub = lane & 15;
    int slot = lane >> 4;
    int cntfull = cursor[v];
    int cnt = cntfull > CAP ? CAP : cntfull;
    const unsigned* bk = bucket + (size_t)v * CAP;
    const float inv = 1.0f / 32767.0f;

    float a0=0,a1=0,a2=0,a3=0,a4=0,a5=0,a6=0,a7=0;
    int o = slot;
    for (; o + 4 < cnt; o += 8) {
        unsigned p0 = bk[o], p1 = bk[o + 4];
        uint4 g0 = *(const uint4*)(hb + (size_t)(p0 & 0xFFFF) * DFEAT + sub * 8);
        uint4 g1 = *(const uint4*)(hb + (size_t)(p1 & 0xFFFF) * DFEAT + sub * 8);
        float e0 = (float)((int)p0 >> 16) * inv;
        float e1 = (float)((int)p1 >> 16) * inv;
        a0 += blo(g0.x) * e0 + blo(g1.x) * e1;
        a1 += bhi(g0.x) * e0 + bhi(g1.x) * e1;
        a2 += blo(g0.y) * e0 + blo(g1.y) * e1;
        a3 += bhi(g0.y) * e0 + bhi(g1.y) * e1;
        a4 += blo(g0.z) * e0 + blo(g1.z) * e1;
        a5 += bhi(g0.z) * e0 + bhi(g1.z) * e1;
        a6 += blo(g0.w) * e0 + blo(g1.w) * e1;
        a7 += bhi(g0.w) * e0 + bhi(g1.w) * e1;
    }
    for (; o < cnt; o += 4) {
        unsigned p = bk[o];
        uint4 g = *(const uint4*)(hb + (size_t)(p & 0xFFFF) * DFEAT + sub * 8);
        float e = (float)((int)p >> 16) * inv;
        a0 += blo(g.x) * e; a1 += bhi(g.x) * e;
        a2 += blo(g.y) * e; a3 += bhi(g.y) * e;
        a4 += blo(g.z) * e; a5 += bhi(g.z) * e;
        a6 += blo(g.w) * e; a7 += bhi(g.w) * e;
    }

    a0 += __shfl_xor(a0, 16, 64); a1 += __shfl_xor(a1, 16, 64);
    a2 += __shfl_xor(a2, 16, 64); a3 += __shfl_xor(a3, 16, 64);
    a4 += __shfl_xor(a4, 16, 64); a5 += __shfl_xor(a5, 16, 64);
    a6 += __shfl_xor(a6, 16, 64); a7 += __shfl_xor(a7, 16, 64);
    a0 += __shfl_xor(a0, 32, 64); a1 += __shfl_xor(a1, 32, 64);
    a2 += __shfl_xor(a2, 32, 64); a3 += __shfl_xor(a3, 32, 64);
    a4 += __shfl_xor(a4, 32, 64); a5 += __shfl_xor(a5, 32, 64);
    a6 += __shfl_xor(a6, 32, 64); a7 += __shfl_xor(a7, 32, 64);

    if (slot == 0) {
        int n = *ovf_cnt; if (n > OVF_CAP) n = OVF_CAP;   // ~always 0..tens
        for (int t = 0; t < n; t++) {
            int4 p = ovf[t];
            if (p.x == v) {
                float e;
                if (p.w) { float2 A = ad[p.x]; float2 B = bd[p.y];
                           e = tanhf(A.x + B.x) * A.y * B.y; }
                else e = __int_as_float(p.z);
                uint4 g = *(const uint4*)(hb + (size_t)p.y * DFEAT + sub * 8);
                a0 += blo(g.x) * e; a1 += bhi(g.x) * e;
                a2 += blo(g.y) * e; a3 += bhi(g.y) * e;
                a4 += blo(g.z) * e; a5 += bhi(g.z) * e;
                a6 += blo(g.w) * e; a7 += bhi(g.w) * e;
            }
        }
        float* zp = z + (size_t)v * DFEAT + sub * 8;
        *(float4*)zp       = make_float4(a0, a1, a2, a3);
        *(float4*)(zp + 4) = make_float4(a4, a5, a6, a7);
    }
}

// ---- aggregate (fp32 h fallback). lane&31 = float4 chunk, lane>>5 = slot. ----
__global__ void __launch_bounds__(256) aggregate_f32(
        const float* __restrict__ h,
        const unsigned* __restrict__ bucket,
        const int* __restrict__ cursor,
        const float2* __restrict__ ad, const float2* __restrict__ bd,
        const int4* __restrict__ ovf, const int* __restrict__ ovf_cnt,
        float* __restrict__ z, int N) {
    int wid = threadIdx.x >> 6;
    int v = blockIdx.x * 4 + wid;
    if (v >= N) return;
    int lane = threadIdx.x & 63;
    int sub = lane & 31;
    int slot = lane >> 5;
    int cntfull = cursor[v];
    int cnt = cntfull > CAP ? CAP : cntfull;
    const unsigned* bk = bucket + (size_t)v * CAP;
    const float inv = 1.0f / 32767.0f;

    float4 acc = make_float4(0.f, 0.f, 0.f, 0.f);
    int o = slot;
    for (; o + 6 < cnt; o += 8) {
        unsigned p0 = bk[o], p1 = bk[o + 2], p2 = bk[o + 4], p3 = bk[o + 6];
        float4 g0 = *(const float4*)(h + (size_t)(p0 & 0xFFFF) * DFEAT + sub * 4);
        float4 g1 = *(const float4*)(h + (size_t)(p1 & 0xFFFF) * DFEAT + sub * 4);
        float4 g2 = *(const float4*)(h + (size_t)(p2 & 0xFFFF) * DFEAT + sub * 4);
        float4 g3 = *(const float4*)(h + (size_t)(p3 & 0xFFFF) * DFEAT + sub * 4);
        float e0 = (float)((int)p0 >> 16) * inv;
        float e1 = (float)((int)p1 >> 16) * inv;
        float e2 = (float)((int)p2 >> 16) * inv;
        float e3 = (float)((int)p3 >> 16) * inv;
        acc.x += g0.x * e0 + g1.x * e1 + g2.x * e2 + g3.x * e3;
        acc.y += g0.y * e0 + g1.y * e1 + g2.y * e2 + g3.y * e3;
        acc.z += g0.z * e0 + g1.z * e1 + g2.z * e2 + g3.z * e3;
        acc.w += g0.w * e0 + g1.w * e1 + g2.w * e2 + g3.w * e3;
    }
    for (; o < cnt; o += 2) {
        unsigned p = bk[o];
        float4 g = *(const float4*)(h + (size_t)(p & 0xFFFF) * DFEAT + sub * 4);
        float e = (float)((int)p >> 16) * inv;
        acc.x += g.x * e; acc.y += g.y * e; acc.z += g.z * e; acc.w += g.w * e;
    }

    acc.x += __shfl_xor(acc.x, 32, 64);
    acc.y += __shfl_xor(acc.y, 32, 64);
    acc.z += __shfl_xor(acc.z, 32, 64);
    acc.w += __shfl_xor(acc.w, 32, 64);

    if (slot == 0) {
        int n = *ovf_cnt; if (n > OVF_CAP) n = OVF_CAP;
        for (int t = 0; t < n; t++) {
            int4 p = ovf[t];
            if (p.x == v) {
                float e;
                if (p.w) { float2 A = ad[p.x]; float2 B = bd[p.y];
                           e = tanhf(A.x + B.x) * A.y * B.y; }
                else e = __int_as_float(p.z);
                float4 g = *(const float4*)(h + (size_t)p.y * DFEAT + sub * 4);
                acc.x += g.x * e; acc.y += g.y * e;
                acc.z += g.z * e; acc.w += g.w * e;
            }
        }
        *(float4*)(z + (size_t)v * DFEAT + sub * 4) = acc;
    }
}

extern "C" void kernel_launch(void* const* d_in, const int* in_sizes, int n_in,
                              void* d_out, int out_size, void* d_ws, size_t ws_size,
                              hipStream_t stream) {
    const float* h      = (const float*)d_in[0];
    const float* deg    = (const float*)d_in[1];
    const float* gate_w = (const float*)d_in[2];
    const float* gate_b = (const float*)d_in[3];
    const void*  src    = d_in[4];
    const void*  dst    = d_in[5];
    float* z = (float*)d_out;

    const int N = in_sizes[1];   // 50000 (< 65536 required for 16-bit src pack)
    const int E = in_sizes[4];   // 800000
    const int nbins = (N + (1 << BIN_SHIFT) - 1) >> BIN_SHIFT;   // 49

    auto align_up = [](size_t x) { return (x + 255) & ~(size_t)255; };
    size_t off = 0;
    auto carve = [&](size_t bytes) { size_t o = off; off += align_up(bytes); return o; };
    char* base = (char*)d_ws;
    float2*   ad      = (float2*)(base + carve((size_t)N * 8));
    float2*   bd      = (float2*)(base + carve((size_t)N * 8));
    int*      cursor  = (int*)(base + carve((size_t)N * 4));
    int*      subcur  = (int*)(base + carve((size_t)NBINS_MAX * 4));     // 256B
    int*      ovf_cnt = (int*)(base + carve(256));
    unsigned* bucket  = (unsigned*)(base + carve((size_t)N * CAP * 4));
    unsigned* binbuf  = (unsigned*)(base + carve((size_t)NBINS_MAX * BINCAP * 4));
    int4*     ovf     = (int4*)(base + carve((size_t)OVF_CAP * 16));
    // core ~12.7 MB. hb goes last, only if it FITS:
    size_t hb_off = carve((size_t)N * DFEAT * 2);
    bool use_bf16 = (off <= ws_size);        // exact check against ws_size
    unsigned short* hb = use_bf16 ? (unsigned short*)(base + hb_off) : nullptr;

    // zero subcur + ovf_cnt (contiguous 512B)
    hipMemsetAsync(subcur, 0, 512, stream);

    int scb = (E + 256 * EPT - 1) / (256 * EPT);   // 391 binscatter blocks
    int prepBlocks = 1536;
    fused_kernel<<<scb + prepBlocks, 256, 0, stream>>>(
        h, deg, gate_w, gate_b, src, dst, ad, bd, hb,
        subcur, ovf_cnt, ovf, binbuf, N, E, scb, prepBlocks);

    permute_kernel<<<nbins, 1024, 0, stream>>>(binbuf, subcur, ad, bd, cursor,
                                               ovf_cnt, ovf, bucket, N);

    if (use_bf16) {
        aggregate_bf16<<<(N + 3) / 4, 256, 0, stream>>>(hb, bucket, cursor, ad, bd,
                                                        ovf, ovf_cnt, z, N);
    } else {
        aggregate_f32<<<(N + 3) / 4, 256, 0, stream>>>(h, bucket, cursor, ad, bd,
                                                       ovf, ovf_cnt, z, N);
    }
}